// Round 25
// baseline (64.530 us; speedup 1.0000x reference)
//
#include <hip/hip_runtime.h>
#include <math.h>

// Problem constants
#define BB 16384
#define TT 99
#define RR 10
#define LL 3
#define SEG 33           // 99 = 3 segments of 33 steps

// DPP cross-lane (VALU pipe):
#define QP(v, j) __int_as_float(__builtin_amdgcn_mov_dpp(                     \
    __float_as_int(v), (j) * 0x55, 0xF, 0xF, true))
#define HMIR(v)  __int_as_float(__builtin_amdgcn_mov_dpp(                     \
    __float_as_int(v), 0x141, 0xF, 0xF, true))

// 8-lane full-h gather: 11 DPP ops (verified R15+).
__device__ __forceinline__ void gather10(float hoA, float hoB, float (&hg)[RR]) {
    hg[0] = QP(hoA, 0); hg[1] = QP(hoA, 1);
    hg[2] = QP(hoA, 2); hg[3] = QP(hoA, 3);
    const float mr = HMIR(hoA);
    hg[4] = QP(mr, 0);  hg[5] = QP(mr, 1);
    hg[6] = QP(mr, 2);  hg[7] = QP(mr, 3);
    hg[8] = QP(hoB, 0); hg[9] = QP(hoB, 1);
}

// One recurrence update from gathered h (identical fp ops everywhere so
// checkpointed h is bit-exact across pass boundaries).
__device__ __forceinline__ void rnn_update(
    int sel, float& hoA, float& hoB, const float (&hg)[RR],
    const float (&UA)[RR], const float (&UB)[RR],
    float cA1, float cA2, float cB1, float cB2)
{
    const bool is1 = (sel == 1);
    float aA0 = is1 ? cA1 : cA2, aB0 = is1 ? cB1 : cB2;
    float aA1 = 0.0f, aB1 = 0.0f;
#pragma unroll
    for (int i = 0; i < 5; ++i) {
        aA0 = fmaf(hg[i],     UA[i],     aA0);
        aA1 = fmaf(hg[5 + i], UA[5 + i], aA1);
        aB0 = fmaf(hg[i],     UB[i],     aB0);
        aB1 = fmaf(hg[5 + i], UB[5 + i], aB1);
    }
    const float eA = __expf(2.0f * (aA0 + aA1));
    const float eB = __expf(2.0f * (aB0 + aB1));
    const float pA = eA + 1.0f, pB = eB + 1.0f;
    const float r  = __builtin_amdgcn_rcpf(pA * pB);
    const float hnA = fmaf(-2.0f * pB, r, 1.0f);
    const float hnB = fmaf(-2.0f * pA, r, 1.0f);
    if (sel != 0) { hoA = hnA; hoB = hnB; }       // Keras masking: carry h
}

// Linear logit emit (zero trans); y embedded in l0's low 2 mantissa bits.
__device__ __forceinline__ void logit_emit(
    const float (&hg)[RR], int yv, int u, int g,
    const float (&Wc)[RR], float boc, float* __restrict__ srow)
{
    float lg = boc;
#pragma unroll
    for (int i = 0; i < RR; ++i) lg = fmaf(hg[i], Wc[i], lg);
    if (g == 0) lg = __int_as_float((__float_as_int(lg) & ~3) | yv);
    if (g < 3) srow[u * LL + g] = lg;             // imm-offset ds_write
}

// shared per-lane weight setup (quad-dependent gather order)
__device__ __forceinline__ void setup_weights(
    int g, const float* U, const float* W, const float* emb, const float* bvec,
    float (&UA)[RR], float (&UB)[RR], int& jA, int& jB,
    float& cA1, float& cA2, float& cB1, float& cB2)
{
    const int qpar = g >> 2;
    int ord[8];
#pragma unroll
    for (int j = 0; j < 4; ++j) {
        ord[j]     = qpar ? 4 + j : j;
        ord[4 + j] = qpar ? 3 - j : 7 - j;
    }
    jA = g;
    jB = ((g & 3) < 2) ? 8 + (g & 3) : 8;
#pragma unroll
    for (int k2 = 0; k2 < 8; ++k2) {
        UA[k2] = U[ord[k2] * RR + jA];
        UB[k2] = U[ord[k2] * RR + jB];
    }
    UA[8] = U[8 * RR + jA]; UA[9] = U[9 * RR + jA];
    UB[8] = U[8 * RR + jB]; UB[9] = U[9 * RR + jB];

    cA1 = bvec[jA]; cA2 = cA1; cB1 = bvec[jB]; cB2 = cB1;
#pragma unroll
    for (int i = 0; i < RR; ++i) {
        const float e1 = emb[RR + i];
        const float e2 = emb[2 * RR + i];
        const float wA = W[i * RR + jA];
        const float wB = W[i * RR + jB];
        cA1 = fmaf(e1, wA, cA1); cA2 = fmaf(e2, wA, cA2);
        cB1 = fmaf(e1, wB, cB1); cB2 = fmaf(e2, wB, cB2);
    }
}

// =================== PASS 1: checkpoints at t=32,65 ===================
// Lightweight recurrence (no stores in loop, no logits) over steps 0..65.
// Checkpoints land in the states buffer at their natural positions (pass 2
// rewrites them with identical bits). 512x256 = 2048 waves.
__global__ __launch_bounds__(256, 2)
void rnn_pass1(const int* __restrict__ tok_ids,
               const float* __restrict__ emb,
               const float* __restrict__ W,
               const float* __restrict__ U,
               const float* __restrict__ bvec,
               float* __restrict__ states_out)
{
    __shared__ unsigned char s_tk[4][8 * 66];

    const int tid = threadIdx.x;
    const int w   = tid >> 6;
    const int l   = tid & 63;
    const int r8  = l >> 3;
    const int g   = l & 7;
    const int rowbase = blockIdx.x * 32 + w * 8;

    // stage tokens for steps 0..65 (per-wave slice, no barrier)
#pragma unroll
    for (int i = 0; i < 9; ++i) {
        const int p = l + 64 * i;
        if (p < 8 * 66) {
            const int r = p / 66;
            const int t = p - r * 66;
            s_tk[w][r * 66 + t] =
                (unsigned char)tok_ids[(size_t)(rowbase + r) * TT + t];
        }
    }

    const unsigned char* cp = &s_tk[w][r8 * 66];
    uint64_t w0 = 0, w1 = 0;
#pragma unroll
    for (int t = 0; t < 32; ++t)
        w0 |= (uint64_t)(cp[t] & 3) << (2 * t);
    const int s32 = (int)cp[32];
#pragma unroll
    for (int t = 33; t < 65; ++t)
        w1 |= (uint64_t)(cp[t] & 3) << (2 * (t - 33));
    const int s65 = (int)cp[65];

    float UA[RR], UB[RR];
    int jA, jB;
    float cA1, cA2, cB1, cB2;
    setup_weights(g, U, W, emb, bvec, UA, UB, jA, jB, cA1, cA2, cB1, cB2);

    const int row = rowbase + r8;
    float* outA = states_out + (size_t)row * (TT * RR) + jA;
    float* outB = states_out + (size_t)row * (TT * RR) + jB;

    float hoA = 0.0f, hoB = 0.0f;

    // steps 0..31
#pragma unroll
    for (int u = 0; u < 32; ++u) {
        const int sel = (int)(w0 & 3); w0 >>= 2;
        float hg[RR]; gather10(hoA, hoB, hg);
        rnn_update(sel, hoA, hoB, hg, UA, UB, cA1, cA2, cB1, cB2);
    }
    // step 32 + checkpoint
    { float hg[RR]; gather10(hoA, hoB, hg);
      rnn_update(s32, hoA, hoB, hg, UA, UB, cA1, cA2, cB1, cB2); }
    outA[32 * RR] = hoA;
    if (g < 2) outB[32 * RR] = hoB;
    // steps 33..64
#pragma unroll
    for (int u = 0; u < 32; ++u) {
        const int sel = (int)(w1 & 3); w1 >>= 2;
        float hg[RR]; gather10(hoA, hoB, hg);
        rnn_update(sel, hoA, hoB, hg, UA, UB, cA1, cA2, cB1, cB2);
    }
    // step 65 + checkpoint
    { float hg[RR]; gather10(hoA, hoB, hg);
      rnn_update(s65, hoA, hoB, hg, UA, UB, cA1, cA2, cB1, cB2); }
    outA[65 * RR] = hoA;
    if (g < 2) outB[65 * RR] = hoB;
}

// ============ PASS 2: 3-way segment-parallel heavy recurrence ============
// Block = (seg, row-block): 3 x 512 = 1536 blocks = 6144 waves = 6 waves/SIMD.
// Each runs 33 steps (states direct stores + linear logits -> LDS -> flush).
__global__ __launch_bounds__(256, 6)
void rnn_pass2(const int* __restrict__ tok_ids,
               const float* __restrict__ labels,
               const float* __restrict__ emb,
               const float* __restrict__ W,
               const float* __restrict__ U,
               const float* __restrict__ bvec,
               const float* __restrict__ Wo,
               const float* __restrict__ bo,
               float* __restrict__ states_out,
               float* __restrict__ logits_out)
{
    __shared__ __align__(8) float   s_lg[4][8 * SEG * LL];   // 12,672 B
    __shared__ unsigned char        s_code[4][8 * 34];       //  1,088 B

    const int seg  = blockIdx.x / 512;        // 0..2
    const int rbk  = blockIdx.x - seg * 512;  // row-block
    const int base = seg * SEG;               // first step of segment

    const int tid = threadIdx.x;
    const int w   = tid >> 6;
    const int l   = tid & 63;
    const int r8  = l >> 3;
    const int g   = l & 7;
    const int rowbase = rbk * 32 + w * 8;

    // stage code bytes for steps base..base+32 (per-wave slice)
#pragma unroll
    for (int i = 0; i < 5; ++i) {
        const int p = l + 64 * i;
        if (p < 8 * 33) {
            const int r = p / 33;
            const int t = p - r * 33;
            const size_t gi = (size_t)(rowbase + r) * TT + base + t;
            const int   tk  = tok_ids[gi];
            const float la1 = labels[gi * LL + 1];
            const float la2 = labels[gi * LL + 2];
            const int   y   = (la1 > 0.5f) ? 1 : ((la2 > 0.5f) ? 2 : 0);
            s_code[w][r * 34 + t] = (unsigned char)((tk << 2) | y);
        }
    }

    // per-lane packs: sel u=0..31 in wsel (+s32); y for emits in wy slots 1..31
    const unsigned char* cp = &s_code[w][r8 * 34];
    uint64_t wsel = 0, wy = 0;
#pragma unroll
    for (int u = 0; u < 32; ++u)
        wsel |= (uint64_t)((cp[u] >> 2) & 3) << (2 * u);
    const int s32 = (int)((cp[32] >> 2) & 3);
#pragma unroll
    for (int u = 1; u < 32; ++u)
        wy |= (uint64_t)(cp[u - 1] & 3) << (2 * u);
    const int y31 = (int)(cp[31] & 3);
    const int y32 = (int)(cp[32] & 3);

    float UA[RR], UB[RR];
    int jA, jB;
    float cA1, cA2, cB1, cB2;
    setup_weights(g, U, W, emb, bvec, UA, UB, jA, jB, cA1, cA2, cB1, cB2);

    // Wc permuted to match hg order (same ord as setup)
    const int qpar = g >> 2;
    const int gc = ((g & 3) < 2) ? (g & 3) : 2;
    float Wc[RR];
#pragma unroll
    for (int j = 0; j < 4; ++j) {
        const int o0 = qpar ? 4 + j : j;
        const int o1 = qpar ? 3 - j : 7 - j;
        Wc[j]     = Wo[o0 * LL + gc];
        Wc[4 + j] = Wo[o1 * LL + gc];
    }
    Wc[8] = Wo[8 * LL + gc]; Wc[9] = Wo[9 * LL + gc];
    const float boc = bo[gc];

    const int row = rowbase + r8;
    float* outA = states_out + (size_t)row * (TT * RR) + base * RR + jA;
    float* outB = states_out + (size_t)row * (TT * RR) + base * RR + jB;
    float* srow = &s_lg[w][r8 * (SEG * LL)];

    // segment start state: 0 for seg 0, else checkpoint from pass 1
    float hoA = 0.0f, hoB = 0.0f;
    if (seg > 0) {
        const size_t ck = (size_t)row * (TT * RR) + (size_t)(base - 1) * RR;
        hoA = states_out[ck + jA];
        hoB = states_out[ck + jB];
    }

    // 32 heavy steps (emit logit u-1 at iteration u>0)
#pragma unroll
    for (int u = 0; u < 32; ++u) {
        const int sel = (int)(wsel & 3); wsel >>= 2;
        const int yv  = (int)(wy & 3);   wy >>= 2;
        float hg[RR]; gather10(hoA, hoB, hg);
        if (u > 0) logit_emit(hg, yv, u - 1, g, Wc, boc, srow);
        rnn_update(sel, hoA, hoB, hg, UA, UB, cA1, cA2, cB1, cB2);
        outA[u * RR] = hoA;
        if (g < 2) outB[u * RR] = hoB;
    }
    // step u=32: emit logit 31, update, store; then final logit 32
    {
        float hg[RR]; gather10(hoA, hoB, hg);
        logit_emit(hg, y31, 31, g, Wc, boc, srow);
        rnn_update(s32, hoA, hoB, hg, UA, UB, cA1, cA2, cB1, cB2);
        outA[32 * RR] = hoA;
        if (g < 2) outB[32 * RR] = hoB;
        float hg2[RR]; gather10(hoA, hoB, hg2);
        logit_emit(hg2, y32, 32, g, Wc, boc, srow);
    }

    // flush logits: 8 rows x 99 floats; contiguous per row (coalesced runs).
    // Same-wave DS ordering: no barrier needed.
#pragma unroll
    for (int i = 0; i < 13; ++i) {
        const int q = l + 64 * i;
        if (q < 8 * SEG * LL) {
            const int r = q / 99;                 // compile-time divisor
            const int m = q - r * 99;
            logits_out[(size_t)(rowbase + r) * (TT * LL) + base * LL + m] =
                s_lg[w][r * 99 + m];
        }
    }
}

// ========== K2: in-place softmax over logits + loss/acc partials ==========
__global__ __launch_bounds__(256)
void softmax_kernel(float* __restrict__ probs,        // in: logits, out: probs
                    float* __restrict__ ws)
{
    const int NT     = BB * TT;
    const int tid    = blockIdx.x * 256 + threadIdx.x;
    const int stride = 2048 * 256;

    float loss = 0.0f;
    int   corr = 0;

#pragma unroll 1
    for (int idx = tid; idx < NT; idx += stride) {
        float* pp = probs + (size_t)idx * LL;
        const float l0 = pp[0], l1 = pp[1], l2 = pp[2];
        const int   y  = __float_as_int(l0) & 3;

        const float e0 = __expf(l0), e1 = __expf(l1), e2 = __expf(l2);
        const float S  = e0 + e1 + e2;
        const float rs = __builtin_amdgcn_rcpf(S);
        pp[0] = e0 * rs; pp[1] = e1 * rs; pp[2] = e2 * rs;

        const float ly = (y == 0) ? l0 : ((y == 1) ? l1 : l2);
        loss += fminf(__logf(S) - ly, 16.11809565f);

        int ap = 0; float pm = l0;
        if (l1 > pm) { ap = 1; pm = l1; }
        if (l2 > pm) { ap = 2; }
        corr += (ap == y) ? 1 : 0;
    }

    __shared__ float sl[4], sc[4];
    float ls = loss, cs = (float)corr;
#pragma unroll
    for (int off = 32; off > 0; off >>= 1) {
        ls += __shfl_down(ls, off, 64);
        cs += __shfl_down(cs, off, 64);
    }
    if ((threadIdx.x & 63) == 0) { sl[threadIdx.x >> 6] = ls; sc[threadIdx.x >> 6] = cs; }
    __syncthreads();
    if (threadIdx.x == 0) {
        ws[blockIdx.x]        = sl[0] + sl[1] + sl[2] + sl[3];
        ws[2048 + blockIdx.x] = sc[0] + sc[1] + sc[2] + sc[3];
    }
}

__global__ __launch_bounds__(256)
void finalize_kernel(const float* __restrict__ ws, float* __restrict__ out_tail)
{
    __shared__ float sl[4], sc[4];
    const int t = threadIdx.x;
    float ls = 0.0f, cs = 0.0f;
#pragma unroll
    for (int i = 0; i < 8; ++i) {
        ls += ws[t + 256 * i];
        cs += ws[2048 + t + 256 * i];
    }
#pragma unroll
    for (int off = 32; off > 0; off >>= 1) {
        ls += __shfl_down(ls, off, 64);
        cs += __shfl_down(cs, off, 64);
    }
    if ((t & 63) == 0) { sl[t >> 6] = ls; sc[t >> 6] = cs; }
    __syncthreads();
    if (t == 0) {
        const float L = sl[0] + sl[1] + sl[2] + sl[3];
        const float C = sc[0] + sc[1] + sc[2] + sc[3];
        const float inv = 1.0f / (float)((size_t)BB * TT);
        out_tail[0] = C * inv;   // accuracy
        out_tail[1] = L * inv;   // loss
    }
}

extern "C" void kernel_launch(void* const* d_in, const int* in_sizes, int n_in,
                              void* d_out, int out_size, void* d_ws, size_t ws_size,
                              hipStream_t stream)
{
    const int*   tok    = (const int*)  d_in[0];
    const float* labels = (const float*)d_in[1];
    // d_in[2] = mask (unused by reference math)
    const float* emb = (const float*)d_in[3];
    const float* W   = (const float*)d_in[4];
    const float* U   = (const float*)d_in[5];
    const float* bv  = (const float*)d_in[6];
    const float* Wo  = (const float*)d_in[7];
    const float* bo  = (const float*)d_in[8];

    float* out    = (float*)d_out;
    float* states = out;                                  // [B,T,10]
    float* probs  = out + (size_t)BB * TT * RR;           // [B,T,3] (logits first)
    float* tail   = out + (size_t)BB * TT * (RR + LL);    // accuracy, loss
    float* ws     = (float*)d_ws;                         // 4096 floats used

    rnn_pass1<<<512, 256, 0, stream>>>(tok, emb, W, U, bv, states);
    rnn_pass2<<<1536, 256, 0, stream>>>(tok, labels, emb, W, U, bv, Wo, bo,
                                        states, probs);
    softmax_kernel<<<2048, 256, 0, stream>>>(probs, ws);
    finalize_kernel<<<1, 256, 0, stream>>>(ws, tail);
}

// Round 26
// 61.880 us; speedup vs baseline: 1.0428x; 1.0428x over previous
//
#include <hip/hip_runtime.h>
#include <math.h>

// Problem constants
#define BB 16384
#define TT 99
#define RR 10
#define LL 3
#define SEG 33           // 99 = 3 segments of 33 steps

// DPP cross-lane (VALU pipe):
#define QP(v, j) __int_as_float(__builtin_amdgcn_mov_dpp(                     \
    __float_as_int(v), (j) * 0x55, 0xF, 0xF, true))
#define HMIR(v)  __int_as_float(__builtin_amdgcn_mov_dpp(                     \
    __float_as_int(v), 0x141, 0xF, 0xF, true))

// 8-lane full-h gather: 11 DPP ops (verified R15+).
__device__ __forceinline__ void gather10(float hoA, float hoB, float (&hg)[RR]) {
    hg[0] = QP(hoA, 0); hg[1] = QP(hoA, 1);
    hg[2] = QP(hoA, 2); hg[3] = QP(hoA, 3);
    const float mr = HMIR(hoA);
    hg[4] = QP(mr, 0);  hg[5] = QP(mr, 1);
    hg[6] = QP(mr, 2);  hg[7] = QP(mr, 3);
    hg[8] = QP(hoB, 0); hg[9] = QP(hoB, 1);
}

// One recurrence update from gathered h (identical fp ops everywhere so
// checkpointed h is bit-exact across pass boundaries).
__device__ __forceinline__ void rnn_update(
    int sel, float& hoA, float& hoB, const float (&hg)[RR],
    const float (&UA)[RR], const float (&UB)[RR],
    float cA1, float cA2, float cB1, float cB2)
{
    const bool is1 = (sel == 1);
    float aA0 = is1 ? cA1 : cA2, aB0 = is1 ? cB1 : cB2;
    float aA1 = 0.0f, aB1 = 0.0f;
#pragma unroll
    for (int i = 0; i < 5; ++i) {
        aA0 = fmaf(hg[i],     UA[i],     aA0);
        aA1 = fmaf(hg[5 + i], UA[5 + i], aA1);
        aB0 = fmaf(hg[i],     UB[i],     aB0);
        aB1 = fmaf(hg[5 + i], UB[5 + i], aB1);
    }
    const float eA = __expf(2.0f * (aA0 + aA1));
    const float eB = __expf(2.0f * (aB0 + aB1));
    const float pA = eA + 1.0f, pB = eB + 1.0f;
    const float r  = __builtin_amdgcn_rcpf(pA * pB);
    const float hnA = fmaf(-2.0f * pB, r, 1.0f);
    const float hnB = fmaf(-2.0f * pA, r, 1.0f);
    if (sel != 0) { hoA = hnA; hoB = hnB; }       // Keras masking: carry h
}

// Linear logit emit (zero trans); y embedded in l0's low 2 mantissa bits.
__device__ __forceinline__ void logit_emit(
    const float (&hg)[RR], int yv, int u, int g,
    const float (&Wc)[RR], float boc, float* __restrict__ srow)
{
    float lg = boc;
#pragma unroll
    for (int i = 0; i < RR; ++i) lg = fmaf(hg[i], Wc[i], lg);
    if (g == 0) lg = __int_as_float((__float_as_int(lg) & ~3) | yv);
    if (g < 3) srow[u * LL + g] = lg;             // imm-offset ds_write
}

// shared per-lane weight setup (quad-dependent gather order)
__device__ __forceinline__ void setup_weights(
    int g, const float* U, const float* W, const float* emb, const float* bvec,
    float (&UA)[RR], float (&UB)[RR], int& jA, int& jB,
    float& cA1, float& cA2, float& cB1, float& cB2)
{
    const int qpar = g >> 2;
    int ord[8];
#pragma unroll
    for (int j = 0; j < 4; ++j) {
        ord[j]     = qpar ? 4 + j : j;
        ord[4 + j] = qpar ? 3 - j : 7 - j;
    }
    jA = g;
    jB = ((g & 3) < 2) ? 8 + (g & 3) : 8;
#pragma unroll
    for (int k2 = 0; k2 < 8; ++k2) {
        UA[k2] = U[ord[k2] * RR + jA];
        UB[k2] = U[ord[k2] * RR + jB];
    }
    UA[8] = U[8 * RR + jA]; UA[9] = U[9 * RR + jA];
    UB[8] = U[8 * RR + jB]; UB[9] = U[9 * RR + jB];

    cA1 = bvec[jA]; cA2 = cA1; cB1 = bvec[jB]; cB2 = cB1;
#pragma unroll
    for (int i = 0; i < RR; ++i) {
        const float e1 = emb[RR + i];
        const float e2 = emb[2 * RR + i];
        const float wA = W[i * RR + jA];
        const float wB = W[i * RR + jB];
        cA1 = fmaf(e1, wA, cA1); cA2 = fmaf(e2, wA, cA2);
        cB1 = fmaf(e1, wB, cB1); cB2 = fmaf(e2, wB, cB2);
    }
}

// =================== PASS 1: checkpoints at t=32,65 ===================
// Lightweight recurrence (no stores in loop, no logits) over steps 0..65.
__global__ __launch_bounds__(256, 2)
void rnn_pass1(const int* __restrict__ tok_ids,
               const float* __restrict__ emb,
               const float* __restrict__ W,
               const float* __restrict__ U,
               const float* __restrict__ bvec,
               float* __restrict__ states_out)
{
    __shared__ unsigned char s_tk[4][8 * 66];

    const int tid = threadIdx.x;
    const int w   = tid >> 6;
    const int l   = tid & 63;
    const int r8  = l >> 3;
    const int g   = l & 7;
    const int rowbase = blockIdx.x * 32 + w * 8;

    // stage tokens for steps 0..65 (per-wave slice, no barrier)
#pragma unroll
    for (int i = 0; i < 9; ++i) {
        const int p = l + 64 * i;
        if (p < 8 * 66) {
            const int r = p / 66;
            const int t = p - r * 66;
            s_tk[w][r * 66 + t] =
                (unsigned char)tok_ids[(size_t)(rowbase + r) * TT + t];
        }
    }

    const unsigned char* cp = &s_tk[w][r8 * 66];
    uint64_t w0 = 0, w1 = 0;
#pragma unroll
    for (int t = 0; t < 32; ++t)
        w0 |= (uint64_t)(cp[t] & 3) << (2 * t);
    const int s32 = (int)cp[32];
#pragma unroll
    for (int t = 33; t < 65; ++t)
        w1 |= (uint64_t)(cp[t] & 3) << (2 * (t - 33));
    const int s65 = (int)cp[65];

    float UA[RR], UB[RR];
    int jA, jB;
    float cA1, cA2, cB1, cB2;
    setup_weights(g, U, W, emb, bvec, UA, UB, jA, jB, cA1, cA2, cB1, cB2);

    const int row = rowbase + r8;
    float* outA = states_out + (size_t)row * (TT * RR) + jA;
    float* outB = states_out + (size_t)row * (TT * RR) + jB;

    float hoA = 0.0f, hoB = 0.0f;

    // steps 0..31
#pragma unroll
    for (int u = 0; u < 32; ++u) {
        const int sel = (int)(w0 & 3); w0 >>= 2;
        float hg[RR]; gather10(hoA, hoB, hg);
        rnn_update(sel, hoA, hoB, hg, UA, UB, cA1, cA2, cB1, cB2);
    }
    // step 32 + checkpoint
    { float hg[RR]; gather10(hoA, hoB, hg);
      rnn_update(s32, hoA, hoB, hg, UA, UB, cA1, cA2, cB1, cB2); }
    outA[32 * RR] = hoA;
    if (g < 2) outB[32 * RR] = hoB;
    // steps 33..64
#pragma unroll
    for (int u = 0; u < 32; ++u) {
        const int sel = (int)(w1 & 3); w1 >>= 2;
        float hg[RR]; gather10(hoA, hoB, hg);
        rnn_update(sel, hoA, hoB, hg, UA, UB, cA1, cA2, cB1, cB2);
    }
    // step 65 + checkpoint
    { float hg[RR]; gather10(hoA, hoB, hg);
      rnn_update(s65, hoA, hoB, hg, UA, UB, cA1, cA2, cB1, cB2); }
    outA[65 * RR] = hoA;
    if (g < 2) outB[65 * RR] = hoB;
}

// ============ PASS 2: 3-way segment-parallel heavy recurrence ============
// Block = (seg, row-block): 3 x 512 = 1536 blocks = 6 blocks/CU = 24 waves/CU
// = 6 waves/SIMD co-resident -- PROVIDED the allocator isn't strangled:
// R26 FIX: launch_bounds(256,2), not (256,6). R25's (256,6) capped VGPR at
// 40 -> scratch spills in the hot loop -> 53us at VALUBusy 13%.
__global__ __launch_bounds__(256, 2)
void rnn_pass2(const int* __restrict__ tok_ids,
               const float* __restrict__ labels,
               const float* __restrict__ emb,
               const float* __restrict__ W,
               const float* __restrict__ U,
               const float* __restrict__ bvec,
               const float* __restrict__ Wo,
               const float* __restrict__ bo,
               float* __restrict__ states_out,
               float* __restrict__ logits_out)
{
    __shared__ __align__(8) float   s_lg[4][8 * SEG * LL];   // 12,672 B
    __shared__ unsigned char        s_code[4][8 * 34];       //  1,088 B

    const int seg  = blockIdx.x / 512;        // 0..2
    const int rbk  = blockIdx.x - seg * 512;  // row-block
    const int base = seg * SEG;               // first step of segment

    const int tid = threadIdx.x;
    const int w   = tid >> 6;
    const int l   = tid & 63;
    const int r8  = l >> 3;
    const int g   = l & 7;
    const int rowbase = rbk * 32 + w * 8;

    // stage code bytes for steps base..base+32 (per-wave slice)
#pragma unroll
    for (int i = 0; i < 5; ++i) {
        const int p = l + 64 * i;
        if (p < 8 * 33) {
            const int r = p / 33;
            const int t = p - r * 33;
            const size_t gi = (size_t)(rowbase + r) * TT + base + t;
            const int   tk  = tok_ids[gi];
            const float la1 = labels[gi * LL + 1];
            const float la2 = labels[gi * LL + 2];
            const int   y   = (la1 > 0.5f) ? 1 : ((la2 > 0.5f) ? 2 : 0);
            s_code[w][r * 34 + t] = (unsigned char)((tk << 2) | y);
        }
    }

    // per-lane packs: sel u=0..31 in wsel (+s32); y for emits in wy slots 1..31
    const unsigned char* cp = &s_code[w][r8 * 34];
    uint64_t wsel = 0, wy = 0;
#pragma unroll
    for (int u = 0; u < 32; ++u)
        wsel |= (uint64_t)((cp[u] >> 2) & 3) << (2 * u);
    const int s32 = (int)((cp[32] >> 2) & 3);
#pragma unroll
    for (int u = 1; u < 32; ++u)
        wy |= (uint64_t)(cp[u - 1] & 3) << (2 * u);
    const int y31 = (int)(cp[31] & 3);
    const int y32 = (int)(cp[32] & 3);

    float UA[RR], UB[RR];
    int jA, jB;
    float cA1, cA2, cB1, cB2;
    setup_weights(g, U, W, emb, bvec, UA, UB, jA, jB, cA1, cA2, cB1, cB2);

    // Wc permuted to match hg order (same ord as setup)
    const int qpar = g >> 2;
    const int gc = ((g & 3) < 2) ? (g & 3) : 2;
    float Wc[RR];
#pragma unroll
    for (int j = 0; j < 4; ++j) {
        const int o0 = qpar ? 4 + j : j;
        const int o1 = qpar ? 3 - j : 7 - j;
        Wc[j]     = Wo[o0 * LL + gc];
        Wc[4 + j] = Wo[o1 * LL + gc];
    }
    Wc[8] = Wo[8 * LL + gc]; Wc[9] = Wo[9 * LL + gc];
    const float boc = bo[gc];

    const int row = rowbase + r8;
    float* outA = states_out + (size_t)row * (TT * RR) + base * RR + jA;
    float* outB = states_out + (size_t)row * (TT * RR) + base * RR + jB;
    float* srow = &s_lg[w][r8 * (SEG * LL)];

    // segment start state: 0 for seg 0, else checkpoint from pass 1
    float hoA = 0.0f, hoB = 0.0f;
    if (seg > 0) {
        const size_t ck = (size_t)row * (TT * RR) + (size_t)(base - 1) * RR;
        hoA = states_out[ck + jA];
        hoB = states_out[ck + jB];
    }

    // 32 heavy steps (emit logit u-1 at iteration u>0)
#pragma unroll
    for (int u = 0; u < 32; ++u) {
        const int sel = (int)(wsel & 3); wsel >>= 2;
        const int yv  = (int)(wy & 3);   wy >>= 2;
        float hg[RR]; gather10(hoA, hoB, hg);
        if (u > 0) logit_emit(hg, yv, u - 1, g, Wc, boc, srow);
        rnn_update(sel, hoA, hoB, hg, UA, UB, cA1, cA2, cB1, cB2);
        outA[u * RR] = hoA;
        if (g < 2) outB[u * RR] = hoB;
    }
    // step u=32: emit logit 31, update, store; then final logit 32
    {
        float hg[RR]; gather10(hoA, hoB, hg);
        logit_emit(hg, y31, 31, g, Wc, boc, srow);
        rnn_update(s32, hoA, hoB, hg, UA, UB, cA1, cA2, cB1, cB2);
        outA[32 * RR] = hoA;
        if (g < 2) outB[32 * RR] = hoB;
        float hg2[RR]; gather10(hoA, hoB, hg2);
        logit_emit(hg2, y32, 32, g, Wc, boc, srow);
    }

    // flush logits: 8 rows x 99 floats; contiguous per row (coalesced runs).
#pragma unroll
    for (int i = 0; i < 13; ++i) {
        const int q = l + 64 * i;
        if (q < 8 * SEG * LL) {
            const int r = q / 99;                 // compile-time divisor
            const int m = q - r * 99;
            logits_out[(size_t)(rowbase + r) * (TT * LL) + base * LL + m] =
                s_lg[w][r * 99 + m];
        }
    }
}

// ========== K2: in-place softmax over logits + loss/acc partials ==========
__global__ __launch_bounds__(256)
void softmax_kernel(float* __restrict__ probs,        // in: logits, out: probs
                    float* __restrict__ ws)
{
    const int NT     = BB * TT;
    const int tid    = blockIdx.x * 256 + threadIdx.x;
    const int stride = 2048 * 256;

    float loss = 0.0f;
    int   corr = 0;

#pragma unroll 1
    for (int idx = tid; idx < NT; idx += stride) {
        float* pp = probs + (size_t)idx * LL;
        const float l0 = pp[0], l1 = pp[1], l2 = pp[2];
        const int   y  = __float_as_int(l0) & 3;

        const float e0 = __expf(l0), e1 = __expf(l1), e2 = __expf(l2);
        const float S  = e0 + e1 + e2;
        const float rs = __builtin_amdgcn_rcpf(S);
        pp[0] = e0 * rs; pp[1] = e1 * rs; pp[2] = e2 * rs;

        const float ly = (y == 0) ? l0 : ((y == 1) ? l1 : l2);
        loss += fminf(__logf(S) - ly, 16.11809565f);

        int ap = 0; float pm = l0;
        if (l1 > pm) { ap = 1; pm = l1; }
        if (l2 > pm) { ap = 2; }
        corr += (ap == y) ? 1 : 0;
    }

    __shared__ float sl[4], sc[4];
    float ls = loss, cs = (float)corr;
#pragma unroll
    for (int off = 32; off > 0; off >>= 1) {
        ls += __shfl_down(ls, off, 64);
        cs += __shfl_down(cs, off, 64);
    }
    if ((threadIdx.x & 63) == 0) { sl[threadIdx.x >> 6] = ls; sc[threadIdx.x >> 6] = cs; }
    __syncthreads();
    if (threadIdx.x == 0) {
        ws[blockIdx.x]        = sl[0] + sl[1] + sl[2] + sl[3];
        ws[2048 + blockIdx.x] = sc[0] + sc[1] + sc[2] + sc[3];
    }
}

__global__ __launch_bounds__(256)
void finalize_kernel(const float* __restrict__ ws, float* __restrict__ out_tail)
{
    __shared__ float sl[4], sc[4];
    const int t = threadIdx.x;
    float ls = 0.0f, cs = 0.0f;
#pragma unroll
    for (int i = 0; i < 8; ++i) {
        ls += ws[t + 256 * i];
        cs += ws[2048 + t + 256 * i];
    }
#pragma unroll
    for (int off = 32; off > 0; off >>= 1) {
        ls += __shfl_down(ls, off, 64);
        cs += __shfl_down(cs, off, 64);
    }
    if ((t & 63) == 0) { sl[t >> 6] = ls; sc[t >> 6] = cs; }
    __syncthreads();
    if (t == 0) {
        const float L = sl[0] + sl[1] + sl[2] + sl[3];
        const float C = sc[0] + sc[1] + sc[2] + sc[3];
        const float inv = 1.0f / (float)((size_t)BB * TT);
        out_tail[0] = C * inv;   // accuracy
        out_tail[1] = L * inv;   // loss
    }
}

extern "C" void kernel_launch(void* const* d_in, const int* in_sizes, int n_in,
                              void* d_out, int out_size, void* d_ws, size_t ws_size,
                              hipStream_t stream)
{
    const int*   tok    = (const int*)  d_in[0];
    const float* labels = (const float*)d_in[1];
    // d_in[2] = mask (unused by reference math)
    const float* emb = (const float*)d_in[3];
    const float* W   = (const float*)d_in[4];
    const float* U   = (const float*)d_in[5];
    const float* bv  = (const float*)d_in[6];
    const float* Wo  = (const float*)d_in[7];
    const float* bo  = (const float*)d_in[8];

    float* out    = (float*)d_out;
    float* states = out;                                  // [B,T,10]
    float* probs  = out + (size_t)BB * TT * RR;           // [B,T,3] (logits first)
    float* tail   = out + (size_t)BB * TT * (RR + LL);    // accuracy, loss
    float* ws     = (float*)d_ws;                         // 4096 floats used

    rnn_pass1<<<512, 256, 0, stream>>>(tok, emb, W, U, bv, states);
    rnn_pass2<<<1536, 256, 0, stream>>>(tok, labels, emb, W, U, bv, Wo, bo,
                                        states, probs);
    softmax_kernel<<<2048, 256, 0, stream>>>(probs, ws);
    finalize_kernel<<<1, 256, 0, stream>>>(ws, tail);
}